// Round 6
// baseline (798.843 us; speedup 1.0000x reference)
//
#include <hip/hip_runtime.h>
#include <math.h>

#define D_ 1024
#define H_ 16
#define HD_ 64
#define BATCH 32
#define NTOK 257
#define NROWS (BATCH*NTOK)     // 8224
#define NE 129
#define NO 128
#define RR 16
#define UNM 113
#define NMERGED 241
#define MROWS (BATCH*NMERGED)  // 7712
#define SELSTRIDE 288

typedef unsigned short u16;
typedef unsigned int u32;
typedef __bf16 bf16x8 __attribute__((ext_vector_type(8)));
typedef float floatx4 __attribute__((ext_vector_type(4)));

__device__ __forceinline__ u16 f2bf(float f) {
    u32 u = __float_as_uint(f);
    u += 0x7fffu + ((u >> 16) & 1u);      // round-to-nearest-even
    return (u16)(u >> 16);
}

// ---------------- LayerNorm: fp32 in, optional fp32 + bf16 out --------------
__global__ __launch_bounds__(256) void ln_kernel(const float* __restrict__ x,
                                                 const float* __restrict__ w,
                                                 const float* __restrict__ bia,
                                                 float* __restrict__ outf,
                                                 u16* __restrict__ outb) {
    int row = blockIdx.x;
    const float* xr = x + (size_t)row * D_;
    int t = threadIdx.x;
    float v[4];
#pragma unroll
    for (int i = 0; i < 4; i++) v[i] = xr[t + 256 * i];
    float s = v[0] + v[1] + v[2] + v[3];
#pragma unroll
    for (int o = 32; o; o >>= 1) s += __shfl_down(s, o);
    __shared__ float sm[8];
    int wv = t >> 6, ln = t & 63;
    if (ln == 0) sm[wv] = s;
    __syncthreads();
    float mu = (sm[0] + sm[1] + sm[2] + sm[3]) * (1.0f / D_);
    float d0 = v[0] - mu, d1 = v[1] - mu, d2 = v[2] - mu, d3 = v[3] - mu;
    float q = d0 * d0 + d1 * d1 + d2 * d2 + d3 * d3;
#pragma unroll
    for (int o = 32; o; o >>= 1) q += __shfl_down(q, o);
    if (ln == 0) sm[4 + wv] = q;
    __syncthreads();
    float var = (sm[4] + sm[5] + sm[6] + sm[7]) * (1.0f / D_);
    float rs = rsqrtf(var + 1e-5f);
#pragma unroll
    for (int i = 0; i < 4; i++) {
        int c = t + 256 * i;
        float o = (v[i] - mu) * rs * w[c] + bia[c];
        if (outf) outf[(size_t)row * D_ + c] = o;
        if (outb) outb[(size_t)row * D_ + c] = f2bf(o);
    }
}

// ------- averaged K-projection weight, TRANSPOSED: WmT[c][d] ---------------
__global__ __launch_bounds__(256) void wm_kernel(const float* __restrict__ W,
                                                 const float* __restrict__ bias,
                                                 float* __restrict__ WmT,
                                                 float* __restrict__ bm) {
    int e = blockIdx.x * 256 + threadIdx.x;
    if (e < 64 * 1024) {
        int d = e >> 10, c = e & 1023;
        float s = 0.f;
#pragma unroll
        for (int hh = 0; hh < 16; hh++)
            s += W[(size_t)(1024 + hh * 64 + d) * 1024 + c];
        WmT[(size_t)c * 64 + d] = s * (1.0f / 16.0f);
    }
    if (e < 64) {
        float s = 0.f;
        for (int hh = 0; hh < 16; hh++) s += bias[1024 + hh * 64 + e];
        bm[e] = s * (1.0f / 16.0f);
    }
}

// ---------------- cast the 4 weight matrices fp32 -> bf16 -------------------
__global__ __launch_bounds__(256) void castw_kernel(const float* __restrict__ s0,
                                                    const float* __restrict__ s1,
                                                    const float* __restrict__ s2,
                                                    const float* __restrict__ s3,
                                                    u16* __restrict__ d0, u16* __restrict__ d1,
                                                    u16* __restrict__ d2, u16* __restrict__ d3) {
    size_t gi = ((size_t)blockIdx.x * 256 + threadIdx.x) * 8;
    const float* s; u16* d; size_t off;
    if (gi < 3145728)        { s = s0; d = d0; off = gi; }
    else if (gi < 4194304)   { s = s1; d = d1; off = gi - 3145728; }
    else if (gi < 8388608)   { s = s2; d = d2; off = gi - 4194304; }
    else                     { s = s3; d = d3; off = gi - 8388608; }
    float4 a = *(const float4*)(s + off);
    float4 b = *(const float4*)(s + off + 4);
    uint4 o;
    o.x = (u32)f2bf(a.x) | ((u32)f2bf(a.y) << 16);
    o.y = (u32)f2bf(a.z) | ((u32)f2bf(a.w) << 16);
    o.z = (u32)f2bf(b.x) | ((u32)f2bf(b.y) << 16);
    o.w = (u32)f2bf(b.z) | ((u32)f2bf(b.w) << 16);
    *(uint4*)(d + off) = o;
}

// ---------------- skinny fp32 metric GEMM: metric = h @ WmT + bm ------------
__global__ __launch_bounds__(256) void metric_kernel(const float* __restrict__ A,
                                                     const float* __restrict__ WmT,
                                                     const float* __restrict__ bm,
                                                     float* __restrict__ metric) {
    int wv = threadIdx.x >> 6, ln = threadIdx.x & 63;
    int row0 = blockIdx.x * 16 + wv * 4;
    const float* a0 = A + (size_t)row0 * 1024;
    float acc0 = 0.f, acc1 = 0.f, acc2 = 0.f, acc3 = 0.f;
    for (int k = 0; k < 1024; k += 8) {
#pragma unroll
        for (int kk = 0; kk < 8; kk++) {
            float w = WmT[(size_t)(k + kk) * 64 + ln];
            acc0 = fmaf(a0[k + kk], w, acc0);
            acc1 = fmaf(a0[1024 + k + kk], w, acc1);
            acc2 = fmaf(a0[2048 + k + kk], w, acc2);
            acc3 = fmaf(a0[3072 + k + kk], w, acc3);
        }
    }
    float b = bm[ln];
    metric[(size_t)row0 * 64 + ln] = acc0 + b;
    metric[(size_t)(row0 + 1) * 64 + ln] = acc1 + b;
    metric[(size_t)(row0 + 2) * 64 + ln] = acc2 + b;
    metric[(size_t)(row0 + 3) * 64 + ln] = acc3 + b;
}

// ---------------- bf16 MFMA GEMM (XOR-swizzled LDS, L2 panel swizzle) -------
// 1D grid of Gx*Gy blocks; remapped into column panels of 8 x-tiles,
// y-fastest inside a panel -> each XCD's L2 holds the panel's B-slice.
__global__ __launch_bounds__(256) void mgemm_kernel(const u16* __restrict__ A,
                                                    const u16* __restrict__ Bw,
                                                    const float* __restrict__ bias,
                                                    const float* __restrict__ resid,
                                                    void* __restrict__ Cv,
                                                    int M, int N, int K, int mode,
                                                    int Gx) {
    __shared__ u16 As[128 * 64];
    __shared__ u16 Bs[128 * 64];
    int tid = threadIdx.x;
    int wv = tid >> 6, ln = tid & 63;
    int Gy = gridDim.x / Gx;
    int lin = blockIdx.x;
    int panelH = 8 * Gy;
    int p = lin / panelH;
    int r = lin - p * panelH;
    int xt = p * 8 + (r & 7);
    int yt = r >> 3;
    int m0 = yt * 128, n0 = xt * 128;
    int sr = wv * 8 + (ln >> 3);
    int sc = ((ln & 7) ^ (ln >> 3)) * 8;
    const u16* Ag[4]; const u16* Bg[4];
#pragma unroll
    for (int i = 0; i < 4; i++) {
        Ag[i] = A + (size_t)(m0 + i * 32 + sr) * K + sc;
        Bg[i] = Bw + (size_t)(n0 + i * 32 + sr) * K + sc;
    }
    floatx4 acc[4][4];
#pragma unroll
    for (int i = 0; i < 4; i++)
#pragma unroll
        for (int j = 0; j < 4; j++) acc[i][j] = (floatx4){0.f, 0.f, 0.f, 0.f};
    int wm = (wv & 1) * 64, wn = (wv >> 1) * 64;
    int lane16 = ln & 15, lq = ln >> 4;
    int sw = lane16 & 7;

    for (int k0 = 0; k0 < K; k0 += 64) {
        __syncthreads();
#pragma unroll
        for (int i = 0; i < 4; i++) {
            __builtin_amdgcn_global_load_lds(
                (const __attribute__((address_space(1))) void*)(Ag[i] + k0),
                (__attribute__((address_space(3))) void*)&As[i * 2048 + wv * 512], 16, 0, 0);
            __builtin_amdgcn_global_load_lds(
                (const __attribute__((address_space(1))) void*)(Bg[i] + k0),
                (__attribute__((address_space(3))) void*)&Bs[i * 2048 + wv * 512], 16, 0, 0);
        }
        __syncthreads();
#pragma unroll
        for (int ks = 0; ks < 2; ks++) {
            bf16x8 af[4], bf[4];
#pragma unroll
            for (int t = 0; t < 4; t++) {
                int slot = ((ks * 4 + lq) ^ sw) * 8;
                af[t] = *(const bf16x8*)&As[(wm + t * 16 + lane16) * 64 + slot];
                bf[t] = *(const bf16x8*)&Bs[(wn + t * 16 + lane16) * 64 + slot];
            }
#pragma unroll
            for (int mt = 0; mt < 4; mt++)
#pragma unroll
                for (int nt = 0; nt < 4; nt++)
                    acc[mt][nt] = __builtin_amdgcn_mfma_f32_16x16x32_bf16(
                        af[mt], bf[nt], acc[mt][nt], 0, 0, 0);
        }
    }
#pragma unroll
    for (int mt = 0; mt < 4; mt++) {
#pragma unroll
        for (int nt = 0; nt < 4; nt++) {
            int col = n0 + wn + nt * 16 + lane16;
            float bv = bias[col];
#pragma unroll
            for (int r2 = 0; r2 < 4; r2++) {
                int row = m0 + wm + mt * 16 + lq * 4 + r2;
                if (row < M) {
                    float v = acc[mt][nt][r2] + bv;
                    if (mode == 1) {
                        ((float*)Cv)[(size_t)row * N + col] = v + resid[(size_t)row * N + col];
                    } else {
                        if (mode == 2) v = 0.5f * v * (1.0f + erff(v * 0.70710678118654752f));
                        ((u16*)Cv)[(size_t)row * N + col] = f2bf(v);
                    }
                }
            }
        }
    }
}

// ---------------- MFMA flash attention ------------------------------------
#define VST 296
#define PST 40
__global__ __launch_bounds__(256, 3) void fattn_kernel(const u16* __restrict__ qkv,
                                                       u16* __restrict__ o) {
    __shared__ __align__(16) u16 Vts[64 * VST];
    __shared__ __align__(16) u16 Pb[4][16 * PST];
    int b = blockIdx.x / H_, h = blockIdx.x % H_;
    int tid = threadIdx.x;
    int wv = tid >> 6, ln = tid & 63;
    int lane16 = ln & 15, lq = ln >> 4;
    const u16* base = qkv + (size_t)b * NTOK * 3072 + h * HD_;

    for (int idx = tid; idx < NTOK * 8; idx += 256) {
        int key = idx >> 3, d0 = (idx & 7) * 8;
        uint4 u = *(const uint4*)(base + (size_t)key * 3072 + 2048 + d0);
        u16 e[8] = {(u16)u.x, (u16)(u.x >> 16), (u16)u.y, (u16)(u.y >> 16),
                    (u16)u.z, (u16)(u.z >> 16), (u16)u.w, (u16)(u.w >> 16)};
#pragma unroll
        for (int i = 0; i < 8; i++) Vts[(d0 + i) * VST + key] = e[i];
    }
    for (int idx = tid; idx < 64 * 32; idx += 256) {
        int d = idx >> 5, c = idx & 31;
        if (c) Vts[d * VST + 256 + c] = 0;
    }
    __syncthreads();

    u16* Pw = &Pb[wv][0];
    for (int qt = wv; qt < 17; qt += 4) {
        int q0 = qt * 16;
        const u16* qp = base + (size_t)(q0 + lane16) * 3072 + lq * 8;
        bf16x8 af0 = *(const bf16x8*)(qp);
        bf16x8 af1 = *(const bf16x8*)(qp + 32);
        floatx4 accs[17];
#pragma unroll
        for (int nt = 0; nt < 17; nt++) {
            const u16* kp = base + (size_t)(nt * 16 + lane16) * 3072 + 1024 + lq * 8;
            bf16x8 kb0 = *(const bf16x8*)(kp);
            bf16x8 kb1 = *(const bf16x8*)(kp + 32);
            floatx4 z = (floatx4){0.f, 0.f, 0.f, 0.f};
            z = __builtin_amdgcn_mfma_f32_16x16x32_bf16(af0, kb0, z, 0, 0, 0);
            accs[nt] = __builtin_amdgcn_mfma_f32_16x16x32_bf16(af1, kb1, z, 0, 0, 0);
        }
        if (lane16 != 0) {
#pragma unroll
            for (int r = 0; r < 4; r++) accs[16][r] = -3.0e38f;
        }
        float mrow[4], lsum[4], inv[4];
#pragma unroll
        for (int r = 0; r < 4; r++) {
            float m = -3.0e38f;
#pragma unroll
            for (int nt = 0; nt < 17; nt++) m = fmaxf(m, accs[nt][r]);
#pragma unroll
            for (int off = 1; off < 16; off <<= 1) m = fmaxf(m, __shfl_xor(m, off));
            mrow[r] = m;
            lsum[r] = 0.f;
        }
#pragma unroll
        for (int nt = 0; nt < 17; nt++) {
#pragma unroll
            for (int r = 0; r < 4; r++) {
                float p = __expf((accs[nt][r] - mrow[r]) * 0.125f);
                accs[nt][r] = p;
                lsum[r] += p;
            }
        }
#pragma unroll
        for (int r = 0; r < 4; r++) {
#pragma unroll
            for (int off = 1; off < 16; off <<= 1) lsum[r] += __shfl_xor(lsum[r], off);
            inv[r] = 1.0f / lsum[r];
        }
        floatx4 acco[4];
#pragma unroll
        for (int dt = 0; dt < 4; dt++) acco[dt] = (floatx4){0.f, 0.f, 0.f, 0.f};
#pragma unroll
        for (int ks = 0; ks < 9; ks++) {
            int nt0 = 2 * ks, nt1 = 2 * ks + 1;
#pragma unroll
            for (int r = 0; r < 4; r++) {
                float p0 = accs[nt0][r];
                float p1 = (nt1 <= 16) ? accs[nt1][r] : 0.f;
                Pw[(lq * 4 + r) * PST + lane16] = f2bf(p0);
                Pw[(lq * 4 + r) * PST + 16 + lane16] = f2bf(p1);
            }
            bf16x8 pa = *(const bf16x8*)&Pw[lane16 * PST + lq * 8];
#pragma unroll
            for (int dt = 0; dt < 4; dt++) {
                bf16x8 vb = *(const bf16x8*)&Vts[(dt * 16 + lane16) * VST + ks * 32 + lq * 8];
                acco[dt] = __builtin_amdgcn_mfma_f32_16x16x32_bf16(pa, vb, acco[dt], 0, 0, 0);
            }
        }
#pragma unroll
        for (int dt = 0; dt < 4; dt++) {
#pragma unroll
            for (int r = 0; r < 4; r++) {
                int row = q0 + lq * 4 + r;
                if (row < NTOK)
                    o[((size_t)(b * NTOK + row)) * D_ + h * HD_ + dt * 16 + lane16] =
                        f2bf(acco[dt][r] * inv[r]);
            }
        }
    }
}

// ---------------- ToME stage 1: normalize metric rows -----------------------
__global__ __launch_bounds__(256) void mnorm_kernel(const float* __restrict__ metric,
                                                    float* __restrict__ aN,
                                                    float* __restrict__ bT) {
    int r = blockIdx.x * 4 + (threadIdx.x >> 6);
    int l = threadIdx.x & 63;
    int b = r / NTOK, t = r % NTOK;
    float v = metric[(size_t)r * 64 + l];
    float ss = v * v;
#pragma unroll
    for (int off = 1; off < 64; off <<= 1) ss += __shfl_xor(ss, off);
    float nv = v * rsqrtf(ss);
    if (!(t & 1)) aN[((size_t)b * NE + (t >> 1)) * 64 + l] = nv;
    else          bT[(size_t)b * 8192 + l * 128 + (t >> 1)] = nv;
}

// ---------------- ToME stage 2: scores + per-even argmax --------------------
__global__ __launch_bounds__(256) void score_kernel(const float* __restrict__ aN,
                                                    const float* __restrict__ bT,
                                                    float* __restrict__ nodeMax,
                                                    int* __restrict__ nodeIdx) {
    __shared__ float aL[4][64];
    int b = blockIdx.x / 33, eb = blockIdx.x % 33;
    int wv = threadIdx.x >> 6, l = threadIdx.x & 63;
    int e = eb * 4 + wv;
    if (e >= NE) return;
    aL[wv][l] = aN[((size_t)b * NE + e) * 64 + l];
    const float* bp = bT + (size_t)b * 8192;
    float s0 = 0.f, s1 = 0.f;
#pragma unroll 8
    for (int c = 0; c < 64; c++) {
        float w = aL[wv][c];
        s0 = fmaf(w, bp[c * 128 + l], s0);
        s1 = fmaf(w, bp[c * 128 + 64 + l], s1);
    }
    float bv; int bj;
    if (s1 > s0) { bv = s1; bj = l + 64; } else { bv = s0; bj = l; }
    if (e == 0) { bv = -3.0e38f; bj = 0; }
#pragma unroll
    for (int off = 1; off < 64; off <<= 1) {
        float ov = __shfl_xor(bv, off);
        int oj = __shfl_xor(bj, off);
        if (ov > bv || (ov == bv && oj < bj)) { bv = ov; bj = oj; }
    }
    if (l == 0) { nodeMax[b * NE + e] = bv; nodeIdx[b * NE + e] = bj; }
}

// ---------------- ToME stage 3: top-16 pick + cnt + unm ---------------------
__global__ __launch_bounds__(64) void pick_kernel(const float* __restrict__ nodeMax,
                                                  const int* __restrict__ nodeIdx,
                                                  int* __restrict__ sel) {
    __shared__ unsigned char usedL[NE];
    __shared__ int cntL[NO];
    int b = blockIdx.x, l = threadIdx.x;
    int* sb = sel + b * SELSTRIDE;
    float v0 = nodeMax[b * NE + l];
    float v1 = nodeMax[b * NE + 64 + l];
    float v2 = (l == 0) ? nodeMax[b * NE + 128] : -3.0e38f;
    u32 usedM = (l == 0) ? 0u : 4u;
    cntL[l] = 0; cntL[l + 64] = 0;
    for (int s = 0; s < RR; s++) {
        float bv = -3.0e38f; int be = 1 << 30;
        if (!(usedM & 1u) && v0 > bv) { bv = v0; be = l; }
        if (!(usedM & 2u) && v1 > bv) { bv = v1; be = l + 64; }
        if (!(usedM & 4u) && v2 > bv) { bv = v2; be = l + 128; }
#pragma unroll
        for (int off = 1; off < 64; off <<= 1) {
            float ov = __shfl_xor(bv, off);
            int oe = __shfl_xor(be, off);
            if (ov > bv || (ov == bv && oe < be)) { bv = ov; be = oe; }
        }
        if ((be & 63) == l) usedM |= 1u << (be >> 6);
        if (l == 0) {
            sb[s] = be;
            int d = nodeIdx[b * NE + be];
            sb[16 + s] = d;
            cntL[d]++;
        }
    }
    usedL[l] = (usedM & 1u) ? 1 : 0;
    usedL[64 + l] = (usedM & 2u) ? 1 : 0;
    if (l == 0) usedL[128] = (usedM & 4u) ? 1 : 0;
    __syncthreads();
    if (l == 0) {
        int u = 0;
        for (int e = 0; e < NE; e++) if (!usedL[e]) sb[160 + u++] = e;
    }
    sb[32 + l] = cntL[l];
    sb[32 + 64 + l] = cntL[l + 64];
}

// ---------------- merge (fp32, unchanged) -----------------------------------
__global__ __launch_bounds__(256) void merge_kernel(const float* __restrict__ x,
                                                    const int* __restrict__ sel,
                                                    float* __restrict__ xm) {
    int blk = blockIdx.x;
    int b = blk / NMERGED, t = blk % NMERGED;
    const int* sb = sel + b * SELSTRIDE;
    int tid = threadIdx.x;
    const float* xb = x + (size_t)b * NTOK * D_;
    float* orow = xm + ((size_t)b * NMERGED + t) * D_;
    if (t < UNM) {
        int srcRow = 2 * sb[160 + t];
        const float* r = xb + (size_t)srcRow * D_;
#pragma unroll
        for (int i = 0; i < 4; i++) orow[tid + 256 * i] = r[tid + 256 * i];
    } else {
        int j = t - UNM;
        const float* r = xb + (size_t)(2 * j + 1) * D_;
        float v[4];
#pragma unroll
        for (int i = 0; i < 4; i++) v[i] = r[tid + 256 * i];
        int c = sb[32 + j];
        if (c > 0) {
            for (int s = 0; s < RR; s++) {
                if (sb[16 + s] == j) {
                    const float* rs = xb + (size_t)(2 * sb[s]) * D_;
#pragma unroll
                    for (int i = 0; i < 4; i++) v[i] += rs[tid + 256 * i];
                }
            }
            float inv = 1.0f / (float)(1 + c);
#pragma unroll
            for (int i = 0; i < 4; i++) v[i] *= inv;
        }
#pragma unroll
        for (int i = 0; i < 4; i++) orow[tid + 256 * i] = v[i];
    }
}

// ---------------------------------------------------------------------------
extern "C" void kernel_launch(void* const* d_in, const int* in_sizes, int n_in,
                              void* d_out, int out_size, void* d_ws, size_t ws_size,
                              hipStream_t stream) {
    (void)in_sizes; (void)n_in; (void)out_size; (void)ws_size;
    const float* qx   = (const float*)d_in[0];
    const float* ln1w = (const float*)d_in[1];
    const float* ln1b = (const float*)d_in[2];
    const float* ipw  = (const float*)d_in[3];
    const float* ipb  = (const float*)d_in[4];
    const float* outw = (const float*)d_in[5];
    const float* outb = (const float*)d_in[6];
    const float* ln2w = (const float*)d_in[7];
    const float* ln2b = (const float*)d_in[8];
    const float* fcw  = (const float*)d_in[9];
    const float* fcb  = (const float*)d_in[10];
    const float* pw   = (const float*)d_in[11];
    const float* pb   = (const float*)d_in[12];
    float* out = (float*)d_out;

    // workspace layout (bytes, 16B-aligned), peak ~196.2 MB
    char* ws = (char*)d_ws;
    u16*   qkvb  = (u16*)(ws + 0);           // 8320x3072 bf16
    u16*   h2b   = (u16*)(ws + 0);           // 7808x4096 bf16 (reuse)
    u16*   hb    = (u16*)(ws + 51118080);    // 8320x1024 bf16
    float* hf    = (float*)(ws + 68157440);  // 8224x1024 f32 (later xbuf)
    float* xbuf  = hf;
    u16*   ob    = (u16*)(ws + 101842944);   // 8320x1024 bf16
    float* metric= (float*)(ws + 118882304); // 8224x64 f32
    float* xm    = (float*)(ws + 120987648); // 7712x1024 f32
    u16*   ln2bb = (u16*)(ws + 152576000);   // 7808x1024 bf16
    u16*   wqkv  = (u16*)(ws + 168566784);   // 3072x1024
    u16*   woutb = (u16*)(ws + 174858240);   // 1024x1024
    u16*   wfc   = (u16*)(ws + 176955392);   // 4096x1024
    u16*   wproj = (u16*)(ws + 185344000);   // 1024x4096
    float* WmT   = (float*)(ws + 193732608); // 1024x64
    float* bm    = (float*)(ws + 193994752); // 64
    int*   sel   = (int*)(ws + 193995008);   // 32x288
    float* aN    = (float*)(ws + 194031872); // 32x129x64 f32
    float* bT    = (float*)(ws + 195088640); // 32x64x128 f32
    float* nMax  = (float*)(ws + 196137216); // 32x129 f32
    int*   nIdx  = (int*)(ws + 196153856);   // 32x129 i32

    // 1. LN1 -> h fp32 (metric path) + h bf16 (MFMA qkv)
    ln_kernel<<<NROWS, 256, 0, stream>>>(qx, ln1w, ln1b, hf, hb);
    // 2. averaged K-projection weight (fp32, transposed)
    wm_kernel<<<256, 256, 0, stream>>>(ipw, ipb, WmT, bm);
    // 3. cast weights to bf16
    castw_kernel<<<6144, 256, 0, stream>>>(ipw, outw, fcw, pw, wqkv, woutb, wfc, wproj);
    // 4. metric = h @ WmT + bm  (fp32-exact skinny GEMM)
    metric_kernel<<<514, 256, 0, stream>>>(hf, WmT, bm, metric);
    // 5. qkv = h @ in_proj_w^T + b   (Gx=24, Gy=65)
    mgemm_kernel<<<24 * 65, 256, 0, stream>>>(hb, wqkv, ipb, nullptr, qkvb,
                                              NROWS, 3072, 1024, 0, 24);
    // 6. MFMA flash attention -> o bf16
    fattn_kernel<<<BATCH * H_, 256, 0, stream>>>(qkvb, ob);
    // 7. x = q_x + o @ out_w^T + out_b (fp32 out)   (Gx=8, Gy=65)
    mgemm_kernel<<<8 * 65, 256, 0, stream>>>(ob, woutb, outb, qx, xbuf,
                                             NROWS, 1024, 1024, 1, 8);
    // 8. ToME: normalize -> scores/argmax -> top-16 pick -> merge
    mnorm_kernel<<<2056, 256, 0, stream>>>(metric, aN, bT);
    score_kernel<<<BATCH * 33, 256, 0, stream>>>(aN, bT, nMax, nIdx);
    pick_kernel<<<BATCH, 64, 0, stream>>>(nMax, nIdx, sel);
    merge_kernel<<<BATCH * NMERGED, 256, 0, stream>>>(xbuf, sel, xm);
    // 9. LN2 -> bf16
    ln_kernel<<<MROWS, 256, 0, stream>>>(xm, ln2w, ln2b, nullptr, ln2bb);
    // 10. fc + gelu -> h2 bf16   (Gx=32, Gy=61)
    mgemm_kernel<<<32 * 61, 256, 0, stream>>>(ln2bb, wfc, fcb, nullptr, h2b,
                                              MROWS, 4096, 1024, 2, 32);
    // 11. out = xm + h2 @ proj_w^T + proj_b   (Gx=8, Gy=61)
    mgemm_kernel<<<8 * 61, 256, 0, stream>>>(h2b, wproj, pb, xm, out,
                                             MROWS, 1024, 4096, 1, 8);
}

// Round 7
// 774.146 us; speedup vs baseline: 1.0319x; 1.0319x over previous
//
#include <hip/hip_runtime.h>
#include <math.h>

#define D_ 1024
#define H_ 16
#define HD_ 64
#define BATCH 32
#define NTOK 257
#define NROWS (BATCH*NTOK)     // 8224
#define NE 129
#define NO 128
#define RR 16
#define UNM 113
#define NMERGED 241
#define MROWS (BATCH*NMERGED)  // 7712
#define SELSTRIDE 288

typedef unsigned short u16;
typedef unsigned int u32;
typedef __bf16 bf16x8 __attribute__((ext_vector_type(8)));
typedef float floatx4 __attribute__((ext_vector_type(4)));

__device__ __forceinline__ u16 f2bf(float f) {
    u32 u = __float_as_uint(f);
    u += 0x7fffu + ((u >> 16) & 1u);      // round-to-nearest-even
    return (u16)(u >> 16);
}

// ---------------- LayerNorm: fp32 in, fp32 + bf16 out (LN1) -----------------
__global__ __launch_bounds__(256) void ln_kernel(const float* __restrict__ x,
                                                 const float* __restrict__ w,
                                                 const float* __restrict__ bia,
                                                 float* __restrict__ outf,
                                                 u16* __restrict__ outb) {
    int row = blockIdx.x;
    const float* xr = x + (size_t)row * D_;
    int t = threadIdx.x;
    float v[4];
#pragma unroll
    for (int i = 0; i < 4; i++) v[i] = xr[t + 256 * i];
    float s = v[0] + v[1] + v[2] + v[3];
#pragma unroll
    for (int o = 32; o; o >>= 1) s += __shfl_down(s, o);
    __shared__ float sm[8];
    int wv = t >> 6, ln = t & 63;
    if (ln == 0) sm[wv] = s;
    __syncthreads();
    float mu = (sm[0] + sm[1] + sm[2] + sm[3]) * (1.0f / D_);
    float d0 = v[0] - mu, d1 = v[1] - mu, d2 = v[2] - mu, d3 = v[3] - mu;
    float q = d0 * d0 + d1 * d1 + d2 * d2 + d3 * d3;
#pragma unroll
    for (int o = 32; o; o >>= 1) q += __shfl_down(q, o);
    if (ln == 0) sm[4 + wv] = q;
    __syncthreads();
    float var = (sm[4] + sm[5] + sm[6] + sm[7]) * (1.0f / D_);
    float rs = rsqrtf(var + 1e-5f);
#pragma unroll
    for (int i = 0; i < 4; i++) {
        int c = t + 256 * i;
        float o = (v[i] - mu) * rs * w[c] + bia[c];
        if (outf) outf[(size_t)row * D_ + c] = o;
        outb[(size_t)row * D_ + c] = f2bf(o);
    }
}

// ------- averaged K-projection weight, TRANSPOSED: WmT[c][d] ---------------
__global__ __launch_bounds__(256) void wm_kernel(const float* __restrict__ W,
                                                 const float* __restrict__ bias,
                                                 float* __restrict__ WmT,
                                                 float* __restrict__ bm) {
    int e = blockIdx.x * 256 + threadIdx.x;
    if (e < 64 * 1024) {
        int d = e >> 10, c = e & 1023;
        float s = 0.f;
#pragma unroll
        for (int hh = 0; hh < 16; hh++)
            s += W[(size_t)(1024 + hh * 64 + d) * 1024 + c];
        WmT[(size_t)c * 64 + d] = s * (1.0f / 16.0f);
    }
    if (e < 64) {
        float s = 0.f;
        for (int hh = 0; hh < 16; hh++) s += bias[1024 + hh * 64 + e];
        bm[e] = s * (1.0f / 16.0f);
    }
}

// ---------------- cast the 4 weight matrices fp32 -> bf16 -------------------
__global__ __launch_bounds__(256) void castw_kernel(const float* __restrict__ s0,
                                                    const float* __restrict__ s1,
                                                    const float* __restrict__ s2,
                                                    const float* __restrict__ s3,
                                                    u16* __restrict__ d0, u16* __restrict__ d1,
                                                    u16* __restrict__ d2, u16* __restrict__ d3) {
    size_t gi = ((size_t)blockIdx.x * 256 + threadIdx.x) * 8;
    const float* s; u16* d; size_t off;
    if (gi < 3145728)        { s = s0; d = d0; off = gi; }
    else if (gi < 4194304)   { s = s1; d = d1; off = gi - 3145728; }
    else if (gi < 8388608)   { s = s2; d = d2; off = gi - 4194304; }
    else                     { s = s3; d = d3; off = gi - 8388608; }
    float4 a = *(const float4*)(s + off);
    float4 b = *(const float4*)(s + off + 4);
    uint4 o;
    o.x = (u32)f2bf(a.x) | ((u32)f2bf(a.y) << 16);
    o.y = (u32)f2bf(a.z) | ((u32)f2bf(a.w) << 16);
    o.z = (u32)f2bf(b.x) | ((u32)f2bf(b.y) << 16);
    o.w = (u32)f2bf(b.z) | ((u32)f2bf(b.w) << 16);
    *(uint4*)(d + off) = o;
}

// ---------------- skinny fp32 metric GEMM: metric = h @ WmT + bm ------------
__global__ __launch_bounds__(256) void metric_kernel(const float* __restrict__ A,
                                                     const float* __restrict__ WmT,
                                                     const float* __restrict__ bm,
                                                     float* __restrict__ metric) {
    int wv = threadIdx.x >> 6, ln = threadIdx.x & 63;
    int row0 = blockIdx.x * 16 + wv * 4;
    const float* a0 = A + (size_t)row0 * 1024;
    float acc0 = 0.f, acc1 = 0.f, acc2 = 0.f, acc3 = 0.f;
    for (int k = 0; k < 1024; k += 8) {
#pragma unroll
        for (int kk = 0; kk < 8; kk++) {
            float w = WmT[(size_t)(k + kk) * 64 + ln];
            acc0 = fmaf(a0[k + kk], w, acc0);
            acc1 = fmaf(a0[1024 + k + kk], w, acc1);
            acc2 = fmaf(a0[2048 + k + kk], w, acc2);
            acc3 = fmaf(a0[3072 + k + kk], w, acc3);
        }
    }
    float b = bm[ln];
    metric[(size_t)row0 * 64 + ln] = acc0 + b;
    metric[(size_t)(row0 + 1) * 64 + ln] = acc1 + b;
    metric[(size_t)(row0 + 2) * 64 + ln] = acc2 + b;
    metric[(size_t)(row0 + 3) * 64 + ln] = acc3 + b;
}

// ---------------- bf16 MFMA GEMM (XOR-swizzled LDS, XCD-aware panels) -------
// MI355X dispatches round-robin over 8 XCDs: XCD = blockIdx % 8. Each XCD
// owns an x-panel of Gx/8 column tiles; its B-slice (<=1MB) stays in its L2.
__global__ __launch_bounds__(256) void mgemm_kernel(const u16* __restrict__ A,
                                                    const u16* __restrict__ Bw,
                                                    const float* __restrict__ bias,
                                                    const float* __restrict__ resid,
                                                    void* __restrict__ Cv,
                                                    int M, int N, int K, int mode,
                                                    int Gx) {
    __shared__ u16 As[128 * 64];
    __shared__ u16 Bs[128 * 64];
    int tid = threadIdx.x;
    int wv = tid >> 6, ln = tid & 63;
    int lin = blockIdx.x;
    int pw = Gx >> 3;                 // panel width (x-tiles per XCD)
    int xcd = lin & 7;
    int j = lin >> 3;
    int xt = xcd * pw + (j % pw);     // x-fastest within panel (A-tile reuse)
    int yt = j / pw;
    int m0 = yt * 128, n0 = xt * 128;
    int sr = wv * 8 + (ln >> 3);
    int sc = ((ln & 7) ^ (ln >> 3)) * 8;
    const u16* Ag[4]; const u16* Bg[4];
#pragma unroll
    for (int i = 0; i < 4; i++) {
        Ag[i] = A + (size_t)(m0 + i * 32 + sr) * K + sc;
        Bg[i] = Bw + (size_t)(n0 + i * 32 + sr) * K + sc;
    }
    floatx4 acc[4][4];
#pragma unroll
    for (int i = 0; i < 4; i++)
#pragma unroll
        for (int j2 = 0; j2 < 4; j2++) acc[i][j2] = (floatx4){0.f, 0.f, 0.f, 0.f};
    int wm = (wv & 1) * 64, wn = (wv >> 1) * 64;
    int lane16 = ln & 15, lq = ln >> 4;
    int sw = lane16 & 7;

    for (int k0 = 0; k0 < K; k0 += 64) {
        __syncthreads();
#pragma unroll
        for (int i = 0; i < 4; i++) {
            __builtin_amdgcn_global_load_lds(
                (const __attribute__((address_space(1))) void*)(Ag[i] + k0),
                (__attribute__((address_space(3))) void*)&As[i * 2048 + wv * 512], 16, 0, 0);
            __builtin_amdgcn_global_load_lds(
                (const __attribute__((address_space(1))) void*)(Bg[i] + k0),
                (__attribute__((address_space(3))) void*)&Bs[i * 2048 + wv * 512], 16, 0, 0);
        }
        __syncthreads();
#pragma unroll
        for (int ks = 0; ks < 2; ks++) {
            bf16x8 af[4], bf[4];
#pragma unroll
            for (int t = 0; t < 4; t++) {
                int slot = ((ks * 4 + lq) ^ sw) * 8;
                af[t] = *(const bf16x8*)&As[(wm + t * 16 + lane16) * 64 + slot];
                bf[t] = *(const bf16x8*)&Bs[(wn + t * 16 + lane16) * 64 + slot];
            }
#pragma unroll
            for (int mt = 0; mt < 4; mt++)
#pragma unroll
                for (int nt = 0; nt < 4; nt++)
                    acc[mt][nt] = __builtin_amdgcn_mfma_f32_16x16x32_bf16(
                        af[mt], bf[nt], acc[mt][nt], 0, 0, 0);
        }
    }
#pragma unroll
    for (int mt = 0; mt < 4; mt++) {
#pragma unroll
        for (int nt = 0; nt < 4; nt++) {
            int col = n0 + wn + nt * 16 + lane16;
            float bv = bias[col];
#pragma unroll
            for (int r2 = 0; r2 < 4; r2++) {
                int row = m0 + wm + mt * 16 + lq * 4 + r2;
                if (row < M) {
                    float v = acc[mt][nt][r2] + bv;
                    if (mode == 1) {
                        ((float*)Cv)[(size_t)row * N + col] = v + resid[(size_t)row * N + col];
                    } else {
                        if (mode == 2) {
                            // tanh-form gelu (cheap; <=1e-3 dev from exact)
                            float u = v * (0.7978845608028654f + 0.0356774081f * v * v);
                            v = v / (1.0f + __expf(-2.0f * u));
                        }
                        ((u16*)Cv)[(size_t)row * N + col] = f2bf(v);
                    }
                }
            }
        }
    }
}

// ---------------- MFMA flash attention ------------------------------------
#define VST 296
#define PST 40
__global__ __launch_bounds__(256, 3) void fattn_kernel(const u16* __restrict__ qkv,
                                                       u16* __restrict__ o) {
    __shared__ __align__(16) u16 Vts[64 * VST];
    __shared__ __align__(16) u16 Pb[4][16 * PST];
    int b = blockIdx.x / H_, h = blockIdx.x % H_;
    int tid = threadIdx.x;
    int wv = tid >> 6, ln = tid & 63;
    int lane16 = ln & 15, lq = ln >> 4;
    const u16* base = qkv + (size_t)b * NTOK * 3072 + h * HD_;

    for (int idx = tid; idx < NTOK * 8; idx += 256) {
        int key = idx >> 3, d0 = (idx & 7) * 8;
        uint4 u = *(const uint4*)(base + (size_t)key * 3072 + 2048 + d0);
        u16 e[8] = {(u16)u.x, (u16)(u.x >> 16), (u16)u.y, (u16)(u.y >> 16),
                    (u16)u.z, (u16)(u.z >> 16), (u16)u.w, (u16)(u.w >> 16)};
#pragma unroll
        for (int i = 0; i < 8; i++) Vts[(d0 + i) * VST + key] = e[i];
    }
    for (int idx = tid; idx < 64 * 32; idx += 256) {
        int d = idx >> 5, c = idx & 31;
        if (c) Vts[d * VST + 256 + c] = 0;
    }
    __syncthreads();

    u16* Pw = &Pb[wv][0];
    for (int qt = wv; qt < 17; qt += 4) {
        int q0 = qt * 16;
        const u16* qp = base + (size_t)(q0 + lane16) * 3072 + lq * 8;
        bf16x8 af0 = *(const bf16x8*)(qp);
        bf16x8 af1 = *(const bf16x8*)(qp + 32);
        floatx4 accs[17];
#pragma unroll
        for (int nt = 0; nt < 17; nt++) {
            const u16* kp = base + (size_t)(nt * 16 + lane16) * 3072 + 1024 + lq * 8;
            bf16x8 kb0 = *(const bf16x8*)(kp);
            bf16x8 kb1 = *(const bf16x8*)(kp + 32);
            floatx4 z = (floatx4){0.f, 0.f, 0.f, 0.f};
            z = __builtin_amdgcn_mfma_f32_16x16x32_bf16(af0, kb0, z, 0, 0, 0);
            accs[nt] = __builtin_amdgcn_mfma_f32_16x16x32_bf16(af1, kb1, z, 0, 0, 0);
        }
        if (lane16 != 0) {
#pragma unroll
            for (int r = 0; r < 4; r++) accs[16][r] = -3.0e38f;
        }
        float mrow[4], lsum[4], inv[4];
#pragma unroll
        for (int r = 0; r < 4; r++) {
            float m = -3.0e38f;
#pragma unroll
            for (int nt = 0; nt < 17; nt++) m = fmaxf(m, accs[nt][r]);
#pragma unroll
            for (int off = 1; off < 16; off <<= 1) m = fmaxf(m, __shfl_xor(m, off));
            mrow[r] = m;
            lsum[r] = 0.f;
        }
#pragma unroll
        for (int nt = 0; nt < 17; nt++) {
#pragma unroll
            for (int r = 0; r < 4; r++) {
                float p = __expf((accs[nt][r] - mrow[r]) * 0.125f);
                accs[nt][r] = p;
                lsum[r] += p;
            }
        }
#pragma unroll
        for (int r = 0; r < 4; r++) {
#pragma unroll
            for (int off = 1; off < 16; off <<= 1) lsum[r] += __shfl_xor(lsum[r], off);
            inv[r] = 1.0f / lsum[r];
        }
        floatx4 acco[4];
#pragma unroll
        for (int dt = 0; dt < 4; dt++) acco[dt] = (floatx4){0.f, 0.f, 0.f, 0.f};
#pragma unroll
        for (int ks = 0; ks < 9; ks++) {
            int nt0 = 2 * ks, nt1 = 2 * ks + 1;
#pragma unroll
            for (int r = 0; r < 4; r++) {
                float p0 = accs[nt0][r];
                float p1 = (nt1 <= 16) ? accs[nt1][r] : 0.f;
                Pw[(lq * 4 + r) * PST + lane16] = f2bf(p0);
                Pw[(lq * 4 + r) * PST + 16 + lane16] = f2bf(p1);
            }
            bf16x8 pa = *(const bf16x8*)&Pw[lane16 * PST + lq * 8];
#pragma unroll
            for (int dt = 0; dt < 4; dt++) {
                bf16x8 vb = *(const bf16x8*)&Vts[(dt * 16 + lane16) * VST + ks * 32 + lq * 8];
                acco[dt] = __builtin_amdgcn_mfma_f32_16x16x32_bf16(pa, vb, acco[dt], 0, 0, 0);
            }
        }
#pragma unroll
        for (int dt = 0; dt < 4; dt++) {
#pragma unroll
            for (int r = 0; r < 4; r++) {
                int row = q0 + lq * 4 + r;
                if (row < NTOK)
                    o[((size_t)(b * NTOK + row)) * D_ + h * HD_ + dt * 16 + lane16] =
                        f2bf(acco[dt][r] * inv[r]);
            }
        }
    }
}

// ---------------- ToME stage 1: normalize metric rows -----------------------
__global__ __launch_bounds__(256) void mnorm_kernel(const float* __restrict__ metric,
                                                    float* __restrict__ aN,
                                                    float* __restrict__ bT) {
    int r = blockIdx.x * 4 + (threadIdx.x >> 6);
    int l = threadIdx.x & 63;
    int b = r / NTOK, t = r % NTOK;
    float v = metric[(size_t)r * 64 + l];
    float ss = v * v;
#pragma unroll
    for (int off = 1; off < 64; off <<= 1) ss += __shfl_xor(ss, off);
    float nv = v * rsqrtf(ss);
    if (!(t & 1)) aN[((size_t)b * NE + (t >> 1)) * 64 + l] = nv;
    else          bT[(size_t)b * 8192 + l * 128 + (t >> 1)] = nv;
}

// ---------------- ToME stage 2: scores + per-even argmax --------------------
__global__ __launch_bounds__(256) void score_kernel(const float* __restrict__ aN,
                                                    const float* __restrict__ bT,
                                                    float* __restrict__ nodeMax,
                                                    int* __restrict__ nodeIdx) {
    __shared__ float aL[4][64];
    int b = blockIdx.x / 33, eb = blockIdx.x % 33;
    int wv = threadIdx.x >> 6, l = threadIdx.x & 63;
    int e = eb * 4 + wv;
    if (e >= NE) return;
    aL[wv][l] = aN[((size_t)b * NE + e) * 64 + l];
    const float* bp = bT + (size_t)b * 8192;
    float s0 = 0.f, s1 = 0.f;
#pragma unroll 8
    for (int c = 0; c < 64; c++) {
        float w = aL[wv][c];
        s0 = fmaf(w, bp[c * 128 + l], s0);
        s1 = fmaf(w, bp[c * 128 + 64 + l], s1);
    }
    float bv; int bj;
    if (s1 > s0) { bv = s1; bj = l + 64; } else { bv = s0; bj = l; }
    if (e == 0) { bv = -3.0e38f; bj = 0; }
#pragma unroll
    for (int off = 1; off < 64; off <<= 1) {
        float ov = __shfl_xor(bv, off);
        int oj = __shfl_xor(bj, off);
        if (ov > bv || (ov == bv && oj < bj)) { bv = ov; bj = oj; }
    }
    if (l == 0) { nodeMax[b * NE + e] = bv; nodeIdx[b * NE + e] = bj; }
}

// ---------------- ToME stage 3: top-16 pick + cnt + unm ---------------------
__global__ __launch_bounds__(64) void pick_kernel(const float* __restrict__ nodeMax,
                                                  const int* __restrict__ nodeIdx,
                                                  int* __restrict__ sel) {
    __shared__ unsigned char usedL[NE];
    __shared__ int cntL[NO];
    int b = blockIdx.x, l = threadIdx.x;
    int* sb = sel + b * SELSTRIDE;
    float v0 = nodeMax[b * NE + l];
    float v1 = nodeMax[b * NE + 64 + l];
    float v2 = (l == 0) ? nodeMax[b * NE + 128] : -3.0e38f;
    u32 usedM = (l == 0) ? 0u : 4u;
    cntL[l] = 0; cntL[l + 64] = 0;
    for (int s = 0; s < RR; s++) {
        float bv = -3.0e38f; int be = 1 << 30;
        if (!(usedM & 1u) && v0 > bv) { bv = v0; be = l; }
        if (!(usedM & 2u) && v1 > bv) { bv = v1; be = l + 64; }
        if (!(usedM & 4u) && v2 > bv) { bv = v2; be = l + 128; }
#pragma unroll
        for (int off = 1; off < 64; off <<= 1) {
            float ov = __shfl_xor(bv, off);
            int oe = __shfl_xor(be, off);
            if (ov > bv || (ov == bv && oe < be)) { bv = ov; be = oe; }
        }
        if ((be & 63) == l) usedM |= 1u << (be >> 6);
        if (l == 0) {
            sb[s] = be;
            int d = nodeIdx[b * NE + be];
            sb[16 + s] = d;
            cntL[d]++;
        }
    }
    usedL[l] = (usedM & 1u) ? 1 : 0;
    usedL[64 + l] = (usedM & 2u) ? 1 : 0;
    if (l == 0) usedL[128] = (usedM & 4u) ? 1 : 0;
    __syncthreads();
    if (l == 0) {
        int u = 0;
        for (int e = 0; e < NE; e++) if (!usedL[e]) sb[160 + u++] = e;
    }
    sb[32 + l] = cntL[l];
    sb[32 + 64 + l] = cntL[l + 64];
}

// ---------------- fused merge + LN2: xm fp32 + ln2 bf16 ---------------------
__global__ __launch_bounds__(256) void merge_ln_kernel(const float* __restrict__ x,
                                                       const int* __restrict__ sel,
                                                       const float* __restrict__ w,
                                                       const float* __restrict__ bia,
                                                       float* __restrict__ xm,
                                                       u16* __restrict__ outb) {
    int blk = blockIdx.x;
    int b = blk / NMERGED, t = blk % NMERGED;
    const int* sb = sel + b * SELSTRIDE;
    int tid = threadIdx.x;
    const float* xb = x + (size_t)b * NTOK * D_;
    float v[4];
    if (t < UNM) {
        int srcRow = 2 * sb[160 + t];
        const float* r = xb + (size_t)srcRow * D_;
#pragma unroll
        for (int i = 0; i < 4; i++) v[i] = r[tid + 256 * i];
    } else {
        int j = t - UNM;
        const float* r = xb + (size_t)(2 * j + 1) * D_;
#pragma unroll
        for (int i = 0; i < 4; i++) v[i] = r[tid + 256 * i];
        int c = sb[32 + j];
        if (c > 0) {
            for (int s = 0; s < RR; s++) {
                if (sb[16 + s] == j) {
                    const float* rs = xb + (size_t)(2 * sb[s]) * D_;
#pragma unroll
                    for (int i = 0; i < 4; i++) v[i] += rs[tid + 256 * i];
                }
            }
            float inv = 1.0f / (float)(1 + c);
#pragma unroll
            for (int i = 0; i < 4; i++) v[i] *= inv;
        }
    }
    // write merged row (needed for proj residual)
    float* orow = xm + (size_t)blk * D_;
#pragma unroll
    for (int i = 0; i < 4; i++) orow[tid + 256 * i] = v[i];
    // fused LN2 -> bf16
    float s = v[0] + v[1] + v[2] + v[3];
#pragma unroll
    for (int o = 32; o; o >>= 1) s += __shfl_down(s, o);
    __shared__ float sm[8];
    int wv = tid >> 6, ln = tid & 63;
    if (ln == 0) sm[wv] = s;
    __syncthreads();
    float mu = (sm[0] + sm[1] + sm[2] + sm[3]) * (1.0f / D_);
    float d0 = v[0] - mu, d1 = v[1] - mu, d2 = v[2] - mu, d3 = v[3] - mu;
    float q = d0 * d0 + d1 * d1 + d2 * d2 + d3 * d3;
#pragma unroll
    for (int o = 32; o; o >>= 1) q += __shfl_down(q, o);
    if (ln == 0) sm[4 + wv] = q;
    __syncthreads();
    float var = (sm[4] + sm[5] + sm[6] + sm[7]) * (1.0f / D_);
    float rs = rsqrtf(var + 1e-5f);
#pragma unroll
    for (int i = 0; i < 4; i++) {
        int c = tid + 256 * i;
        outb[(size_t)blk * D_ + c] = f2bf((v[i] - mu) * rs * w[c] + bia[c]);
    }
}

// ---------------------------------------------------------------------------
extern "C" void kernel_launch(void* const* d_in, const int* in_sizes, int n_in,
                              void* d_out, int out_size, void* d_ws, size_t ws_size,
                              hipStream_t stream) {
    (void)in_sizes; (void)n_in; (void)out_size; (void)ws_size;
    const float* qx   = (const float*)d_in[0];
    const float* ln1w = (const float*)d_in[1];
    const float* ln1b = (const float*)d_in[2];
    const float* ipw  = (const float*)d_in[3];
    const float* ipb  = (const float*)d_in[4];
    const float* outw = (const float*)d_in[5];
    const float* outb = (const float*)d_in[6];
    const float* ln2w = (const float*)d_in[7];
    const float* ln2b = (const float*)d_in[8];
    const float* fcw  = (const float*)d_in[9];
    const float* fcb  = (const float*)d_in[10];
    const float* pw   = (const float*)d_in[11];
    const float* pb   = (const float*)d_in[12];
    float* out = (float*)d_out;

    // workspace layout (bytes, 16B-aligned), peak ~196.2 MB
    char* ws = (char*)d_ws;
    u16*   qkvb  = (u16*)(ws + 0);           // 8320x3072 bf16
    u16*   h2b   = (u16*)(ws + 0);           // 7808x4096 bf16 (reuse)
    u16*   hb    = (u16*)(ws + 51118080);    // 8320x1024 bf16
    float* hf    = (float*)(ws + 68157440);  // 8224x1024 f32 (later xbuf)
    float* xbuf  = hf;
    u16*   ob    = (u16*)(ws + 101842944);   // 8320x1024 bf16
    float* metric= (float*)(ws + 118882304); // 8224x64 f32
    float* xm    = (float*)(ws + 120987648); // 7712x1024 f32
    u16*   ln2bb = (u16*)(ws + 152576000);   // 7808x1024 bf16
    u16*   wqkv  = (u16*)(ws + 168566784);   // 3072x1024
    u16*   woutb = (u16*)(ws + 174858240);   // 1024x1024
    u16*   wfc   = (u16*)(ws + 176955392);   // 4096x1024
    u16*   wproj = (u16*)(ws + 185344000);   // 1024x4096
    float* WmT   = (float*)(ws + 193732608); // 1024x64
    float* bm    = (float*)(ws + 193994752); // 64
    int*   sel   = (int*)(ws + 193995008);   // 32x288
    float* aN    = (float*)(ws + 194031872); // 32x129x64 f32
    float* bT    = (float*)(ws + 195088640); // 32x64x128 f32
    float* nMax  = (float*)(ws + 196137216); // 32x129 f32
    int*   nIdx  = (int*)(ws + 196153856);   // 32x129 i32

    // 1. LN1 -> h fp32 (metric path) + h bf16 (MFMA qkv)
    ln_kernel<<<NROWS, 256, 0, stream>>>(qx, ln1w, ln1b, hf, hb);
    // 2. averaged K-projection weight (fp32, transposed)
    wm_kernel<<<256, 256, 0, stream>>>(ipw, ipb, WmT, bm);
    // 3. cast weights to bf16
    castw_kernel<<<6144, 256, 0, stream>>>(ipw, outw, fcw, pw, wqkv, woutb, wfc, wproj);
    // 4. metric = h @ WmT + bm  (fp32-exact skinny GEMM)
    metric_kernel<<<514, 256, 0, stream>>>(hf, WmT, bm, metric);
    // 5. qkv = h @ in_proj_w^T + b   (Gx=24)
    mgemm_kernel<<<24 * 65, 256, 0, stream>>>(hb, wqkv, ipb, nullptr, qkvb,
                                              NROWS, 3072, 1024, 0, 24);
    // 6. MFMA flash attention -> o bf16
    fattn_kernel<<<BATCH * H_, 256, 0, stream>>>(qkvb, ob);
    // 7. x = q_x + o @ out_w^T + out_b (fp32 out)   (Gx=8)
    mgemm_kernel<<<8 * 65, 256, 0, stream>>>(ob, woutb, outb, qx, xbuf,
                                             NROWS, 1024, 1024, 1, 8);
    // 8. ToME: normalize -> scores/argmax -> top-16 pick -> fused merge+LN2
    mnorm_kernel<<<2056, 256, 0, stream>>>(metric, aN, bT);
    score_kernel<<<BATCH * 33, 256, 0, stream>>>(aN, bT, nMax, nIdx);
    pick_kernel<<<BATCH, 64, 0, stream>>>(nMax, nIdx, sel);
    merge_ln_kernel<<<BATCH * NMERGED, 256, 0, stream>>>(xbuf, sel, ln2w, ln2b, xm, ln2bb);
    // 9. fc + gelu -> h2 bf16   (Gx=32)
    mgemm_kernel<<<32 * 61, 256, 0, stream>>>(ln2bb, wfc, fcb, nullptr, h2b,
                                              MROWS, 4096, 1024, 2, 32);
    // 10. out = xm + h2 @ proj_w^T + proj_b   (Gx=8)
    mgemm_kernel<<<8 * 61, 256, 0, stream>>>(h2b, wproj, pb, xm, out,
                                             MROWS, 1024, 4096, 1, 8);
}